// Round 1
// baseline (1287.727 us; speedup 1.0000x reference)
//
#include <hip/hip_runtime.h>
#include <math.h>

#define S_LEN 1024
#define NHEAD 16
#define HDIM 64
#define LHDIM 16

// ---------------------------------------------------------------------------
// Projection GEMM: O = X @ W + b, output written head-split [B*NH, S, NHD_]
// X: [4096, KDIM] row-major, W: [KDIM, NHD_*16] row-major.
// 64x64 tile, 256 threads, each thread 4x4, K-chunk 16.
// ---------------------------------------------------------------------------
template<int KDIM, int NHD_>
__global__ __launch_bounds__(256)
void proj_kernel(const float* __restrict__ X,
                 const float* __restrict__ W0, const float* __restrict__ B0,
                 const float* __restrict__ W1, const float* __restrict__ B1,
                 const float* __restrict__ W2, const float* __restrict__ B2,
                 float* __restrict__ O0, float* __restrict__ O1, float* __restrict__ O2)
{
    constexpr int NCOLS = NHD_ * NHEAD;
    const float* W; const float* Bi; float* O;
    if (blockIdx.z == 0)      { W = W0; Bi = B0; O = O0; }
    else if (blockIdx.z == 1) { W = W1; Bi = B1; O = O1; }
    else                      { W = W2; Bi = B2; O = O2; }

    __shared__ float As[16][68];   // [k][m] transposed
    __shared__ float Bs[16][68];   // [k][n]

    const int t  = threadIdx.x;
    const int tx = t & 15, ty = t >> 4;
    const int m0 = blockIdx.y << 6;
    const int n0 = blockIdx.x << 6;

    const int mload  = t >> 2;          // X tile: one float4/thread
    const int kload4 = (t & 3) << 2;
    const int kwl    = t >> 4;          // W tile: one float4/thread
    const int nwl4   = (t & 15) << 2;

    float acc[4][4] = {};

    for (int k0 = 0; k0 < KDIM; k0 += 16) {
        float4 xv = *(const float4*)&X[(m0 + mload) * KDIM + k0 + kload4];
        float4 wv = *(const float4*)&W[(k0 + kwl) * NCOLS + n0 + nwl4];
        As[kload4 + 0][mload] = xv.x;
        As[kload4 + 1][mload] = xv.y;
        As[kload4 + 2][mload] = xv.z;
        As[kload4 + 3][mload] = xv.w;
        *(float4*)&Bs[kwl][nwl4] = wv;
        __syncthreads();
        #pragma unroll
        for (int kk = 0; kk < 16; kk++) {
            float4 a4 = *(const float4*)&As[kk][ty << 2];
            float4 b4 = *(const float4*)&Bs[kk][tx << 2];
            float av[4] = {a4.x, a4.y, a4.z, a4.w};
            float bv[4] = {b4.x, b4.y, b4.z, b4.w};
            #pragma unroll
            for (int i = 0; i < 4; i++)
                #pragma unroll
                for (int j = 0; j < 4; j++)
                    acc[i][j] += av[i] * bv[j];
        }
        __syncthreads();
    }

    #pragma unroll
    for (int i = 0; i < 4; i++) {
        int m  = m0 + (ty << 2) + i;
        int bb = m >> 10;          // / S_LEN
        int s  = m & 1023;
        #pragma unroll
        for (int j = 0; j < 4; j++) {
            int n = n0 + (tx << 2) + j;
            int hh = n / NHD_;
            int dd = n % NHD_;
            O[(size_t)(((bb * NHEAD + hh) << 10) + s) * NHD_ + dd] = acc[i][j] + Bi[n];
        }
    }
}

// ---------------------------------------------------------------------------
// Fused dual-stream attention with relative-position bias, flash-style.
// Grid: (S/64, B*NH). 256 threads. q-tile 64 rows, key-tile 64.
// bias[l,r] = q[l] . dist_emb[l-r+2047]; computed per tile as
//   H[lm][c] = q[lm] . E[jb+c],  c in [0,128), jb = l0-r0+1984
//   bias      = H[lm][lm-rn+63]
// ---------------------------------------------------------------------------
__global__ __launch_bounds__(256)
void attn_kernel(const float* __restrict__ qg, const float* __restrict__ kg,
                 const float* __restrict__ vg, const float* __restrict__ lqg,
                 const float* __restrict__ lkg, const float* __restrict__ lvg,
                 const float* __restrict__ maskg, const float* __restrict__ demb,
                 float* __restrict__ octx, float* __restrict__ olctx)
{
    __shared__ float QsT[64][68];    // [d][lm]
    __shared__ float KsT[64][68];    // [d][rn]
    __shared__ float Vs[64][68];     // [rn][d]
    __shared__ float LQsT[16][68];   // [d][lm]
    __shared__ float LKsT[16][68];   // [d][rn]
    __shared__ float LVsT[16][68];   // [d][rn]
    __shared__ float Hs[64][132];    // [lm][c]
    __shared__ float EPs[64 * 132];  // union: EsT[d][c] (stride 132) / Ps[lm][rn] (stride 68)
    __shared__ float Ms[64];

    const int t  = threadIdx.x;
    const int tx = t & 15, ty = t >> 4;
    const int bh = blockIdx.y;
    const int b  = bh >> 4;
    const int h  = bh & 15;
    const int l0 = blockIdx.x << 6;

    const float* qb  = qg  + (size_t)bh * (S_LEN * HDIM);
    const float* kb  = kg  + (size_t)bh * (S_LEN * HDIM);
    const float* vb  = vg  + (size_t)bh * (S_LEN * HDIM);
    const float* lqb = lqg + (size_t)bh * (S_LEN * LHDIM);
    const float* lkb = lkg + (size_t)bh * (S_LEN * LHDIM);
    const float* lvb = lvg + (size_t)bh * (S_LEN * LHDIM);

    // ---- stage Q^T and LQ^T once ----
    #pragma unroll
    for (int r = 0; r < 4; r++) {
        int li = r * 256 + t;
        int m  = li >> 4;
        int d4 = (li & 15) << 2;
        float4 x = *(const float4*)&qb[(l0 + m) * HDIM + d4];
        QsT[d4 + 0][m] = x.x; QsT[d4 + 1][m] = x.y;
        QsT[d4 + 2][m] = x.z; QsT[d4 + 3][m] = x.w;
    }
    {
        int m  = t >> 2;
        int d4 = (t & 3) << 2;
        float4 x = *(const float4*)&lqb[(l0 + m) * LHDIM + d4];
        LQsT[d4 + 0][m] = x.x; LQsT[d4 + 1][m] = x.y;
        LQsT[d4 + 2][m] = x.z; LQsT[d4 + 3][m] = x.w;
    }

    float mrow[4], lrow[4], accl[4];
    float accc[4][4] = {};
    #pragma unroll
    for (int i = 0; i < 4; i++) { mrow[i] = -1e30f; lrow[i] = 0.0f; accl[i] = 0.0f; }

    for (int r0 = 0; r0 < S_LEN; r0 += 64) {
        // ---- stage K^T, V, LK^T, LV^T, E^T, mask ----
        #pragma unroll
        for (int r = 0; r < 4; r++) {
            int li = r * 256 + t;
            int m  = li >> 4;
            int d4 = (li & 15) << 2;
            float4 x = *(const float4*)&kb[(r0 + m) * HDIM + d4];
            KsT[d4 + 0][m] = x.x; KsT[d4 + 1][m] = x.y;
            KsT[d4 + 2][m] = x.z; KsT[d4 + 3][m] = x.w;
            *(float4*)&Vs[m][d4] = *(const float4*)&vb[(r0 + m) * HDIM + d4];
        }
        {
            int m  = t >> 2;
            int d4 = (t & 3) << 2;
            float4 x = *(const float4*)&lkb[(r0 + m) * LHDIM + d4];
            LKsT[d4 + 0][m] = x.x; LKsT[d4 + 1][m] = x.y;
            LKsT[d4 + 2][m] = x.z; LKsT[d4 + 3][m] = x.w;
            float4 y = *(const float4*)&lvb[(r0 + m) * LHDIM + d4];
            LVsT[d4 + 0][m] = y.x; LVsT[d4 + 1][m] = y.y;
            LVsT[d4 + 2][m] = y.z; LVsT[d4 + 3][m] = y.w;
        }
        {
            const int jb = l0 - r0 + 1984;   // dist_emb row of E-slab col 0 (in [1024,2944])
            #pragma unroll
            for (int r = 0; r < 8; r++) {
                int li = r * 256 + t;        // 128 rows x 16 float4
                int c  = li >> 4;
                int d4 = (li & 15) << 2;
                float4 x = *(const float4*)&demb[(jb + c) * HDIM + d4];
                EPs[(d4 + 0) * 132 + c] = x.x;
                EPs[(d4 + 1) * 132 + c] = x.y;
                EPs[(d4 + 2) * 132 + c] = x.z;
                EPs[(d4 + 3) * 132 + c] = x.w;
            }
        }
        if (t < 64) Ms[t] = maskg[b * S_LEN + r0 + t];
        __syncthreads();   // B1: staging visible

        // ---- H = Q @ E^T (64x128x64), rows ty*4.., cols tx*8.. ----
        {
            float hacc[4][8] = {};
            #pragma unroll 8
            for (int d = 0; d < HDIM; d++) {
                float4 q4 = *(const float4*)&QsT[d][ty << 2];
                float4 e0 = *(const float4*)&EPs[d * 132 + (tx << 3)];
                float4 e1 = *(const float4*)&EPs[d * 132 + (tx << 3) + 4];
                float qv[4] = {q4.x, q4.y, q4.z, q4.w};
                float ev[8] = {e0.x, e0.y, e0.z, e0.w, e1.x, e1.y, e1.z, e1.w};
                #pragma unroll
                for (int i = 0; i < 4; i++)
                    #pragma unroll
                    for (int c = 0; c < 8; c++)
                        hacc[i][c] += qv[i] * ev[c];
            }
            #pragma unroll
            for (int i = 0; i < 4; i++) {
                *(float4*)&Hs[(ty << 2) + i][(tx << 3)]     =
                    make_float4(hacc[i][0], hacc[i][1], hacc[i][2], hacc[i][3]);
                *(float4*)&Hs[(ty << 2) + i][(tx << 3) + 4] =
                    make_float4(hacc[i][4], hacc[i][5], hacc[i][6], hacc[i][7]);
            }
        }
        __syncthreads();   // B2: Hs visible; all EsT reads done (Ps may overwrite)

        // ---- scores: (QK^T + bias)/8 + LQLK^T/4 + mask ----
        float sqk[4][4] = {};
        #pragma unroll 8
        for (int d = 0; d < HDIM; d++) {
            float4 q4 = *(const float4*)&QsT[d][ty << 2];
            float4 k4 = *(const float4*)&KsT[d][tx << 2];
            float qv[4] = {q4.x, q4.y, q4.z, q4.w};
            float kv[4] = {k4.x, k4.y, k4.z, k4.w};
            #pragma unroll
            for (int i = 0; i < 4; i++)
                #pragma unroll
                for (int j = 0; j < 4; j++)
                    sqk[i][j] += qv[i] * kv[j];
        }
        float sl[4][4] = {};
        #pragma unroll
        for (int d = 0; d < LHDIM; d++) {
            float4 a4 = *(const float4*)&LQsT[d][ty << 2];
            float4 b4 = *(const float4*)&LKsT[d][tx << 2];
            float av[4] = {a4.x, a4.y, a4.z, a4.w};
            float bv[4] = {b4.x, b4.y, b4.z, b4.w};
            #pragma unroll
            for (int i = 0; i < 4; i++)
                #pragma unroll
                for (int j = 0; j < 4; j++)
                    sl[i][j] += av[i] * bv[j];
        }

        // ---- online softmax (row groups = 16 tx lanes) + write P ----
        #pragma unroll
        for (int i = 0; i < 4; i++) {
            const int lm = (ty << 2) + i;
            float sv[4];
            #pragma unroll
            for (int j = 0; j < 4; j++) {
                int rn = (tx << 2) + j;
                float bias = Hs[lm][lm - rn + 63];
                sv[j] = (sqk[i][j] + bias) * 0.125f + sl[i][j] * 0.25f + Ms[rn];
            }
            float rmax = fmaxf(fmaxf(sv[0], sv[1]), fmaxf(sv[2], sv[3]));
            #pragma unroll
            for (int off = 1; off < 16; off <<= 1)
                rmax = fmaxf(rmax, __shfl_xor(rmax, off));
            float mnew  = fmaxf(mrow[i], rmax);
            float alpha = __expf(mrow[i] - mnew);
            float p0 = __expf(sv[0] - mnew);
            float p1 = __expf(sv[1] - mnew);
            float p2 = __expf(sv[2] - mnew);
            float p3 = __expf(sv[3] - mnew);
            float rsum = p0 + p1 + p2 + p3;
            #pragma unroll
            for (int off = 1; off < 16; off <<= 1)
                rsum += __shfl_xor(rsum, off);
            lrow[i] = lrow[i] * alpha + rsum;
            mrow[i] = mnew;
            accl[i] *= alpha;
            #pragma unroll
            for (int j = 0; j < 4; j++) accc[i][j] *= alpha;
            *(float4*)&EPs[lm * 68 + (tx << 2)] = make_float4(p0, p1, p2, p3);
        }
        __syncthreads();   // B3: Ps visible

        // ---- ctx += P @ V ; lctx += P @ LV ----
        #pragma unroll
        for (int rq = 0; rq < 64; rq += 4) {
            float4 p4[4];
            #pragma unroll
            for (int i = 0; i < 4; i++)
                p4[i] = *(const float4*)&EPs[((ty << 2) + i) * 68 + rq];
            float4 lv4 = *(const float4*)&LVsT[tx][rq];
            float4 v4[4];
            #pragma unroll
            for (int u = 0; u < 4; u++)
                v4[u] = *(const float4*)&Vs[rq + u][tx << 2];
            #pragma unroll
            for (int i = 0; i < 4; i++) {
                float pv[4] = {p4[i].x, p4[i].y, p4[i].z, p4[i].w};
                accc[i][0] += pv[0] * v4[0].x + pv[1] * v4[1].x + pv[2] * v4[2].x + pv[3] * v4[3].x;
                accc[i][1] += pv[0] * v4[0].y + pv[1] * v4[1].y + pv[2] * v4[2].y + pv[3] * v4[3].y;
                accc[i][2] += pv[0] * v4[0].z + pv[1] * v4[1].z + pv[2] * v4[2].z + pv[3] * v4[3].z;
                accc[i][3] += pv[0] * v4[0].w + pv[1] * v4[1].w + pv[2] * v4[2].w + pv[3] * v4[3].w;
                accl[i]    += pv[0] * lv4.x   + pv[1] * lv4.y   + pv[2] * lv4.z   + pv[3] * lv4.w;
            }
        }
        __syncthreads();   // B4: PV reads done, next stage may overwrite
    }

    // ---- epilogue: normalize and store ----
    #pragma unroll
    for (int i = 0; i < 4; i++) {
        int s = l0 + (ty << 2) + i;
        float inv = 1.0f / lrow[i];
        float4 o;
        o.x = accc[i][0] * inv;
        o.y = accc[i][1] * inv;
        o.z = accc[i][2] * inv;
        o.w = accc[i][3] * inv;
        *(float4*)&octx[((size_t)(b * S_LEN + s) << 10) + (h << 6) + (tx << 2)] = o;
        olctx[((size_t)(b * S_LEN + s) << 8) + (h << 4) + tx] = accl[i] * inv;
    }
}

// ---------------------------------------------------------------------------
extern "C" void kernel_launch(void* const* d_in, const int* in_sizes, int n_in,
                              void* d_out, int out_size, void* d_ws, size_t ws_size,
                              hipStream_t stream)
{
    (void)in_sizes; (void)n_in; (void)out_size; (void)ws_size;

    const float* hs   = (const float*)d_in[0];
    const float* lin  = (const float*)d_in[1];
    const float* mask = (const float*)d_in[2];
    const float* wq  = (const float*)d_in[3];  const float* bq  = (const float*)d_in[4];
    const float* wk  = (const float*)d_in[5];  const float* bk  = (const float*)d_in[6];
    const float* wv  = (const float*)d_in[7];  const float* bv  = (const float*)d_in[8];
    const float* lwq = (const float*)d_in[9];  const float* lbq = (const float*)d_in[10];
    const float* lwk = (const float*)d_in[11]; const float* lbk = (const float*)d_in[12];
    const float* lwv = (const float*)d_in[13]; const float* lbv = (const float*)d_in[14];
    const float* demb = (const float*)d_in[15];

    float* ws = (float*)d_ws;
    float* q  = ws;
    float* k  = ws + 4194304;
    float* v  = ws + 8388608;
    float* lq = ws + 12582912;
    float* lk = ws + 13631488;
    float* lv = ws + 14680064;

    proj_kernel<1024, 64><<<dim3(16, 64, 3), 256, 0, stream>>>(
        hs, wq, bq, wk, bk, wv, bv, q, k, v);
    proj_kernel<256, 16><<<dim3(4, 64, 3), 256, 0, stream>>>(
        lin, lwq, lbq, lwk, lbk, lwv, lbv, lq, lk, lv);

    float* octx  = (float*)d_out;
    float* olctx = (float*)d_out + 4194304;
    attn_kernel<<<dim3(16, 64), 256, 0, stream>>>(
        q, k, v, lq, lk, lv, mask, demb, octx, olctx);
}

// Round 2
// 618.259 us; speedup vs baseline: 2.0828x; 2.0828x over previous
//
#include <hip/hip_runtime.h>
#include <math.h>

#define S_LEN 1024
#define NHEAD 16
#define HDIM 64
#define LHDIM 16

typedef __bf16 bf16;
typedef bf16 bf16x8 __attribute__((ext_vector_type(8)));
typedef float f32x4 __attribute__((ext_vector_type(4)));

#define MFMA16(a, b, c) __builtin_amdgcn_mfma_f32_16x16x32_bf16(a, b, c, 0, 0, 0)

// ---------------------------------------------------------------------------
// Projection GEMM: O = (X @ W + b) * scale, bf16 output, head-split layout
// [B*NH, S, NHD_]. X:[4096,KDIM] fp32, W:[KDIM,NHD_*16] fp32.
// ---------------------------------------------------------------------------
template<int KDIM, int NHD_>
__global__ __launch_bounds__(256)
void proj_kernel(const float* __restrict__ X,
                 const float* __restrict__ W0, const float* __restrict__ B0,
                 const float* __restrict__ W1, const float* __restrict__ B1,
                 const float* __restrict__ W2, const float* __restrict__ B2,
                 bf16* __restrict__ O0, bf16* __restrict__ O1, bf16* __restrict__ O2,
                 float s0, float s1, float s2)
{
    constexpr int NCOLS = NHD_ * NHEAD;
    const float* W; const float* Bi; bf16* O; float scale;
    if (blockIdx.z == 0)      { W = W0; Bi = B0; O = O0; scale = s0; }
    else if (blockIdx.z == 1) { W = W1; Bi = B1; O = O1; scale = s1; }
    else                      { W = W2; Bi = B2; O = O2; scale = s2; }

    __shared__ float As[16][68];   // [k][m]
    __shared__ float Bs[16][68];   // [k][n]

    const int t  = threadIdx.x;
    const int tx = t & 15, ty = t >> 4;
    const int m0 = blockIdx.y << 6;
    const int n0 = blockIdx.x << 6;

    const int mload  = t >> 2;
    const int kload4 = (t & 3) << 2;
    const int kwl    = t >> 4;
    const int nwl4   = (t & 15) << 2;

    float acc[4][4] = {};

    for (int k0 = 0; k0 < KDIM; k0 += 16) {
        float4 xv = *(const float4*)&X[(m0 + mload) * KDIM + k0 + kload4];
        float4 wv = *(const float4*)&W[(k0 + kwl) * NCOLS + n0 + nwl4];
        As[kload4 + 0][mload] = xv.x;
        As[kload4 + 1][mload] = xv.y;
        As[kload4 + 2][mload] = xv.z;
        As[kload4 + 3][mload] = xv.w;
        *(float4*)&Bs[kwl][nwl4] = wv;
        __syncthreads();
        #pragma unroll
        for (int kk = 0; kk < 16; kk++) {
            float4 a4 = *(const float4*)&As[kk][ty << 2];
            float4 b4 = *(const float4*)&Bs[kk][tx << 2];
            float av[4] = {a4.x, a4.y, a4.z, a4.w};
            float bv[4] = {b4.x, b4.y, b4.z, b4.w};
            #pragma unroll
            for (int i = 0; i < 4; i++)
                #pragma unroll
                for (int j = 0; j < 4; j++)
                    acc[i][j] += av[i] * bv[j];
        }
        __syncthreads();
    }

    #pragma unroll
    for (int i = 0; i < 4; i++) {
        int m  = m0 + (ty << 2) + i;
        int bb = m >> 10;
        int s  = m & 1023;
        #pragma unroll
        for (int j = 0; j < 4; j++) {
            int n = n0 + (tx << 2) + j;
            int hh = n / NHD_;
            int dd = n % NHD_;
            O[(size_t)(((bb * NHEAD + hh) << 10) + s) * NHD_ + dd] =
                (bf16)((acc[i][j] + Bi[n]) * scale);
        }
    }
}

// fp32 -> bf16 convert (dist_emb)
__global__ __launch_bounds__(256)
void cvt_kernel(const float* __restrict__ in, bf16* __restrict__ out, int n)
{
    int i = blockIdx.x * 256 + threadIdx.x;
    if (i < n) out[i] = (bf16)in[i];
}

// ---------------------------------------------------------------------------
// Fused dual-stream MFMA attention with relative-position bias.
// Grid (S/64, B*NH), 256 threads (4 waves), q-tile 64, k-tile 64.
// Q' = [q*0.125 | lq*0.25 | 0pad]  (96 feat), K' = [k | lk | 0pad].
// scores = Q'.K'^T  (both streams + scaling in one GEMM)
// bias/8 = H[m][m-n+63],  H = Q'[:, :64] @ E^T  (MFMA, 64x128x64 per tile)
// ---------------------------------------------------------------------------
__global__ __launch_bounds__(256)
void attn_kernel(const bf16* __restrict__ qg, const bf16* __restrict__ kg,
                 const bf16* __restrict__ vg, const bf16* __restrict__ lqg,
                 const bf16* __restrict__ lkg, const bf16* __restrict__ lvg,
                 const float* __restrict__ maskg, const bf16* __restrict__ demb,
                 float* __restrict__ octx, float* __restrict__ olctx)
{
    __shared__ bf16 Qs[64][104];    // [m][f] f in [0,96) used
    __shared__ bf16 Ks[64][104];    // [r][f]
    __shared__ bf16 VsT[64][72];    // [d][r]
    __shared__ bf16 LVsT[16][72];   // [d][r]
    __shared__ bf16 EPs[128 * 72];  // union: Es[c][k] stride 72 / Ps[m][r] stride 72
    __shared__ bf16 Hs[64][136];    // [m][c] bias/8
    __shared__ float Ms[64];

    const int t    = threadIdx.x;
    const int w    = t >> 6;
    const int lane = t & 63;
    const int ln   = lane & 15;
    const int quad = lane >> 4;
    const int m0   = w << 4;

    const int bh = blockIdx.y;
    const int b  = bh >> 4;
    const int h  = bh & 15;
    const int l0 = blockIdx.x << 6;

    const bf16* qb  = qg  + (size_t)bh * (S_LEN * HDIM);
    const bf16* kb  = kg  + (size_t)bh * (S_LEN * HDIM);
    const bf16* vb  = vg  + (size_t)bh * (S_LEN * HDIM);
    const bf16* lqb = lqg + (size_t)bh * (S_LEN * LHDIM);
    const bf16* lkb = lkg + (size_t)bh * (S_LEN * LHDIM);
    const bf16* lvb = lvg + (size_t)bh * (S_LEN * LHDIM);

    // ---- stage Q' once: q (scaled at proj), lq, zero-pad ----
    #pragma unroll
    for (int r = 0; r < 2; r++) {
        int li = r * 256 + t;
        int m = li >> 3, o8 = (li & 7) << 3;
        *(bf16x8*)&Qs[m][o8] = *(const bf16x8*)&qb[(l0 + m) * HDIM + o8];
    }
    if (t < 128) {
        int m = t >> 1, o8 = (t & 1) << 3;
        *(bf16x8*)&Qs[m][64 + o8] = *(const bf16x8*)&lqb[(l0 + m) * LHDIM + o8];
    }
    {   // zero pad cols 80..103 of Qs and Ks (Ks pad persists across r0)
        int m = t >> 2, c0 = 80 + (t & 3) * 6;
        #pragma unroll
        for (int u = 0; u < 6; u++) { Qs[m][c0 + u] = (bf16)0.0f; Ks[m][c0 + u] = (bf16)0.0f; }
    }
    __syncthreads();

    // A-fragments of Q' (reused every iteration)
    bf16x8 af[3];
    #pragma unroll
    for (int ks = 0; ks < 3; ks++)
        af[ks] = *(const bf16x8*)&Qs[m0 + ln][ks * 32 + quad * 8];

    float mrow[4], lrow[4];
    f32x4 co[4];
    f32x4 cl;
    #pragma unroll
    for (int i = 0; i < 4; i++) { mrow[i] = -1e30f; lrow[i] = 0.0f; co[i] = (f32x4)0.0f; }
    cl = (f32x4)0.0f;

    for (int r0 = 0; r0 < S_LEN; r0 += 64) {
        // ---- stage K', V^T, LV^T, E, mask ----
        #pragma unroll
        for (int r = 0; r < 2; r++) {
            int li = r * 256 + t;
            int m = li >> 3, o8 = (li & 7) << 3;
            *(bf16x8*)&Ks[m][o8] = *(const bf16x8*)&kb[(r0 + m) * HDIM + o8];
        }
        if (t < 128) {
            int m = t >> 1, o8 = (t & 1) << 3;
            *(bf16x8*)&Ks[m][64 + o8] = *(const bf16x8*)&lkb[(r0 + m) * LHDIM + o8];
        }
        #pragma unroll
        for (int r = 0; r < 2; r++) {
            int li = r * 256 + t;
            int rr = li >> 3, d8 = (li & 7) << 3;
            bf16x8 x = *(const bf16x8*)&vb[(r0 + rr) * HDIM + d8];
            #pragma unroll
            for (int u = 0; u < 8; u++) VsT[d8 + u][rr] = x[u];
        }
        if (t < 128) {
            int rr = t >> 1, d8 = (t & 1) << 3;
            bf16x8 x = *(const bf16x8*)&lvb[(r0 + rr) * LHDIM + d8];
            #pragma unroll
            for (int u = 0; u < 8; u++) LVsT[d8 + u][rr] = x[u];
        }
        {
            const int jb = l0 - r0 + 1984;
            #pragma unroll
            for (int r = 0; r < 4; r++) {
                int li = r * 256 + t;
                int c = li >> 3, o8 = (li & 7) << 3;
                *(bf16x8*)&EPs[c * 72 + o8] = *(const bf16x8*)&demb[(jb + c) * HDIM + o8];
            }
        }
        if (t < 64) Ms[t] = maskg[b * S_LEN + r0 + t];
        __syncthreads();   // B1

        // ---- H = Q'[:, :64] @ E^T : 8 col-tiles ----
        f32x4 hh[8];
        #pragma unroll
        for (int ct = 0; ct < 8; ct++) {
            hh[ct] = (f32x4)0.0f;
            #pragma unroll
            for (int ks = 0; ks < 2; ks++)
                hh[ct] = MFMA16(af[ks],
                                *(const bf16x8*)&EPs[(ct * 16 + ln) * 72 + ks * 32 + quad * 8],
                                hh[ct]);
        }
        // ---- scores = Q' @ K'^T over K=96 ----
        f32x4 sc[4];
        #pragma unroll
        for (int nt = 0; nt < 4; nt++) {
            sc[nt] = (f32x4)0.0f;
            #pragma unroll
            for (int ks = 0; ks < 3; ks++)
                sc[nt] = MFMA16(af[ks],
                                *(const bf16x8*)&Ks[nt * 16 + ln][ks * 32 + quad * 8],
                                sc[nt]);
        }
        // write H (bias/8) to LDS
        #pragma unroll
        for (int ct = 0; ct < 8; ct++)
            #pragma unroll
            for (int reg = 0; reg < 4; reg++)
                Hs[m0 + quad * 4 + reg][ct * 16 + ln] = (bf16)hh[ct][reg];
        __syncthreads();   // B2: Hs visible; Es reads done (Ps may overwrite)

        // ---- softmax (rows = quad*4+reg within wave stripe) ----
        float msv[4];
        #pragma unroll
        for (int nt = 0; nt < 4; nt++) msv[nt] = Ms[nt * 16 + ln];

        float sv[4][4];   // [nt][reg]
        #pragma unroll
        for (int nt = 0; nt < 4; nt++) {
            int n = nt * 16 + ln;
            #pragma unroll
            for (int reg = 0; reg < 4; reg++) {
                int mf = m0 + quad * 4 + reg;
                sv[nt][reg] = sc[nt][reg] + (float)Hs[mf][mf - n + 63] + msv[nt];
            }
        }
        #pragma unroll
        for (int reg = 0; reg < 4; reg++) {
            float rmax = fmaxf(fmaxf(sv[0][reg], sv[1][reg]), fmaxf(sv[2][reg], sv[3][reg]));
            #pragma unroll
            for (int off = 1; off < 16; off <<= 1)
                rmax = fmaxf(rmax, __shfl_xor(rmax, off));
            float mnew  = fmaxf(mrow[reg], rmax);
            float alpha = __expf(mrow[reg] - mnew);
            float rsum = 0.0f;
            #pragma unroll
            for (int nt = 0; nt < 4; nt++) {
                float p = __expf(sv[nt][reg] - mnew);
                sv[nt][reg] = p;
                rsum += p;
            }
            #pragma unroll
            for (int off = 1; off < 16; off <<= 1)
                rsum += __shfl_xor(rsum, off);
            lrow[reg] = lrow[reg] * alpha + rsum;
            mrow[reg] = mnew;
            #pragma unroll
            for (int nt = 0; nt < 4; nt++) co[nt][reg] *= alpha;
            cl[reg] *= alpha;
        }
        // write P (bf16) into Ps region (aliases Es)
        #pragma unroll
        for (int nt = 0; nt < 4; nt++)
            #pragma unroll
            for (int reg = 0; reg < 4; reg++)
                EPs[(m0 + quad * 4 + reg) * 72 + nt * 16 + ln] = (bf16)sv[nt][reg];
        __syncthreads();   // B3: Ps visible

        // ---- ctx += P @ V ; lctx += P @ LV ----
        #pragma unroll
        for (int ks = 0; ks < 2; ks++) {
            bf16x8 ap = *(const bf16x8*)&EPs[(m0 + ln) * 72 + ks * 32 + quad * 8];
            cl = MFMA16(ap, *(const bf16x8*)&LVsT[ln][ks * 32 + quad * 8], cl);
            #pragma unroll
            for (int nt = 0; nt < 4; nt++)
                co[nt] = MFMA16(ap,
                                *(const bf16x8*)&VsT[nt * 16 + ln][ks * 32 + quad * 8],
                                co[nt]);
        }
        __syncthreads();   // B4: PV reads done before next staging
    }

    // ---- epilogue ----
    #pragma unroll
    for (int reg = 0; reg < 4; reg++) {
        int s = l0 + m0 + quad * 4 + reg;
        float inv = 1.0f / lrow[reg];
        #pragma unroll
        for (int nt = 0; nt < 4; nt++)
            octx[(size_t)(b * S_LEN + s) * 1024 + h * 64 + nt * 16 + ln] = co[nt][reg] * inv;
        olctx[(size_t)(b * S_LEN + s) * 256 + h * 16 + ln] = cl[reg] * inv;
    }
}

// ---------------------------------------------------------------------------
extern "C" void kernel_launch(void* const* d_in, const int* in_sizes, int n_in,
                              void* d_out, int out_size, void* d_ws, size_t ws_size,
                              hipStream_t stream)
{
    (void)in_sizes; (void)n_in; (void)out_size; (void)ws_size;

    const float* hs   = (const float*)d_in[0];
    const float* lin  = (const float*)d_in[1];
    const float* mask = (const float*)d_in[2];
    const float* wq  = (const float*)d_in[3];  const float* bq  = (const float*)d_in[4];
    const float* wk  = (const float*)d_in[5];  const float* bk  = (const float*)d_in[6];
    const float* wv  = (const float*)d_in[7];  const float* bv  = (const float*)d_in[8];
    const float* lwq = (const float*)d_in[9];  const float* lbq = (const float*)d_in[10];
    const float* lwk = (const float*)d_in[11]; const float* lbk = (const float*)d_in[12];
    const float* lwv = (const float*)d_in[13]; const float* lbv = (const float*)d_in[14];
    const float* demb = (const float*)d_in[15];

    bf16* ws = (bf16*)d_ws;
    bf16* q  = ws;                    // 4,194,304
    bf16* k  = ws + 4194304;
    bf16* v  = ws + 8388608;
    bf16* lq = ws + 12582912;         // 1,048,576
    bf16* lk = ws + 13631488;
    bf16* lv = ws + 14680064;
    bf16* de = ws + 15728640;         // 262,080

    proj_kernel<1024, 64><<<dim3(16, 64, 3), 256, 0, stream>>>(
        hs, wq, bq, wk, bk, wv, bv, q, k, v, 0.125f, 1.0f, 1.0f);
    proj_kernel<256, 16><<<dim3(4, 64, 3), 256, 0, stream>>>(
        lin, lwq, lbq, lwk, lbk, lwv, lbv, lq, lk, lv, 0.25f, 1.0f, 1.0f);
    cvt_kernel<<<dim3(1024), 256, 0, stream>>>(demb, de, 4095 * HDIM);

    float* octx  = (float*)d_out;
    float* olctx = (float*)d_out + 4194304;
    attn_kernel<<<dim3(16, 64), 256, 0, stream>>>(
        q, k, v, lq, lk, lv, mask, de, octx, olctx);
}

// Round 3
// 308.154 us; speedup vs baseline: 4.1788x; 2.0063x over previous
//
#include <hip/hip_runtime.h>
#include <math.h>

#define S_LEN 1024
#define NHEAD 16
#define HDIM 64
#define LHDIM 16

typedef __bf16 bf16;
typedef bf16 bf16x4 __attribute__((ext_vector_type(4)));
typedef bf16 bf16x8 __attribute__((ext_vector_type(8)));
typedef float f32x4 __attribute__((ext_vector_type(4)));

#define MFMA16(a, b, c) __builtin_amdgcn_mfma_f32_16x16x32_bf16(a, b, c, 0, 0, 0)

// async global->LDS, 16B per lane; lds ptr must be wave-uniform
__device__ __forceinline__ void gl2lds16(const void* g, void* l)
{
    __builtin_amdgcn_global_load_lds(
        (const __attribute__((address_space(1))) unsigned int*)g,
        (__attribute__((address_space(3))) unsigned int*)l,
        16, 0, 0);
}

// ---------------------------------------------------------------------------
// flat fp32 -> bf16 convert (x4 per thread)
// ---------------------------------------------------------------------------
__global__ __launch_bounds__(256)
void cvt4_kernel(const float* __restrict__ in, bf16* __restrict__ out, int n4)
{
    int i = blockIdx.x * 256 + threadIdx.x;
    if (i < n4) {
        float4 v = *(const float4*)&in[(size_t)i * 4];
        bf16x4 o = { (bf16)v.x, (bf16)v.y, (bf16)v.z, (bf16)v.w };
        *(bf16x4*)&out[(size_t)i * 4] = o;
    }
}

// ---------------------------------------------------------------------------
// W [K][N] fp32 -> Wt [N][K] bf16 (LDS-tiled 64x64 transpose)
// ---------------------------------------------------------------------------
__global__ __launch_bounds__(256)
void cvtT_kernel(const float* __restrict__ W0, const float* __restrict__ W1,
                 const float* __restrict__ W2,
                 bf16* __restrict__ T0, bf16* __restrict__ T1, bf16* __restrict__ T2,
                 int K, int N)
{
    const float* W; bf16* T;
    if (blockIdx.z == 0)      { W = W0; T = T0; }
    else if (blockIdx.z == 1) { W = W1; T = T1; }
    else                      { W = W2; T = T2; }

    __shared__ float Ts[64][65];
    const int t  = threadIdx.x;
    const int k0 = blockIdx.y << 6;
    const int n0 = blockIdx.x << 6;

    #pragma unroll
    for (int p = 0; p < 4; p++) {
        int li = p * 256 + t;
        int r  = li >> 4, c4 = (li & 15) << 2;
        float4 v = *(const float4*)&W[(size_t)(k0 + r) * N + n0 + c4];
        Ts[r][c4 + 0] = v.x; Ts[r][c4 + 1] = v.y;
        Ts[r][c4 + 2] = v.z; Ts[r][c4 + 3] = v.w;
    }
    __syncthreads();

    int r2 = t >> 2, ks = (t & 3) << 4;
    bf16x8 o0, o1;
    #pragma unroll
    for (int u = 0; u < 8; u++) o0[u] = (bf16)Ts[ks + u][r2];
    #pragma unroll
    for (int u = 0; u < 8; u++) o1[u] = (bf16)Ts[ks + 8 + u][r2];
    *(bf16x8*)&T[(size_t)(n0 + r2) * K + k0 + ks]     = o0;
    *(bf16x8*)&T[(size_t)(n0 + r2) * K + k0 + ks + 8] = o1;
}

// ---------------------------------------------------------------------------
// MFMA projection GEMM: O = (X @ Wt^T + b) * scale, bf16 out, head-split.
// X: [4096,KDIM] bf16 row-major; Wt: [NCOLS,KDIM] bf16 (pre-transposed).
// 128x128 tile, BK=32, 4 waves x (4x4) mfma_16x16x32, global_load_lds x16.
// ---------------------------------------------------------------------------
template<int KDIM, int NHD_>
__global__ __launch_bounds__(256, 2)
void projm_kernel(const bf16* __restrict__ X,
                  const bf16* __restrict__ Wt0, const float* __restrict__ B0,
                  const bf16* __restrict__ Wt1, const float* __restrict__ B1,
                  const bf16* __restrict__ Wt2, const float* __restrict__ B2,
                  bf16* __restrict__ O0, bf16* __restrict__ O1, bf16* __restrict__ O2,
                  float s0)
{
    const bf16* Wt; const float* Bi; bf16* O; float scale;
    if (blockIdx.z == 0)      { Wt = Wt0; Bi = B0; O = O0; scale = s0; }
    else if (blockIdx.z == 1) { Wt = Wt1; Bi = B1; O = O1; scale = 1.0f; }
    else                      { Wt = Wt2; Bi = B2; O = O2; scale = 1.0f; }

    __shared__ bf16 As[128 * 32];
    __shared__ bf16 Bs[128 * 32];

    const int t    = threadIdx.x;
    const int wv   = t >> 6;
    const int l64  = t & 63;
    const int ln   = l64 & 15;
    const int quad = l64 >> 4;
    const int wm   = wv & 1;
    const int wn   = wv >> 1;
    const int m0   = blockIdx.y << 7;
    const int n0   = blockIdx.x << 7;

    const int arow = l64 >> 2;          // row within 16-row group
    const int koff = (l64 & 3) << 3;    // k offset (x8 bf16)

    f32x4 acc[4][4];
    #pragma unroll
    for (int i = 0; i < 4; i++)
        #pragma unroll
        for (int j = 0; j < 4; j++) acc[i][j] = (f32x4)0.0f;

    for (int k0 = 0; k0 < KDIM; k0 += 32) {
        #pragma unroll
        for (int c = 0; c < 2; c++) {
            int g = (c * 4 + wv) << 4;   // 16-row group base
            gl2lds16(&X [(size_t)(m0 + g + arow) * KDIM + k0 + koff], &As[(c * 4 + wv) * 512]);
            gl2lds16(&Wt[(size_t)(n0 + g + arow) * KDIM + k0 + koff], &Bs[(c * 4 + wv) * 512]);
        }
        __syncthreads();

        bf16x8 af[4], bfv[4];
        #pragma unroll
        for (int mt = 0; mt < 4; mt++)
            af[mt] = *(const bf16x8*)&As[(wm * 64 + mt * 16 + ln) * 32 + quad * 8];
        #pragma unroll
        for (int nt = 0; nt < 4; nt++)
            bfv[nt] = *(const bf16x8*)&Bs[(wn * 64 + nt * 16 + ln) * 32 + quad * 8];
        #pragma unroll
        for (int mt = 0; mt < 4; mt++)
            #pragma unroll
            for (int nt = 0; nt < 4; nt++)
                acc[mt][nt] = MFMA16(af[mt], bfv[nt], acc[mt][nt]);
        __syncthreads();
    }

    // epilogue: bias + scale + head-split bf16 store
    #pragma unroll
    for (int nt = 0; nt < 4; nt++) {
        int n  = n0 + wn * 64 + nt * 16 + ln;
        float bia = Bi[n];
        int hh = n / NHD_;
        int dd = n % NHD_;
        #pragma unroll
        for (int mt = 0; mt < 4; mt++) {
            #pragma unroll
            for (int reg = 0; reg < 4; reg++) {
                int m  = m0 + wm * 64 + mt * 16 + quad * 4 + reg;
                int bb = m >> 10;
                int s  = m & 1023;
                O[((size_t)((bb * NHEAD + hh) << 10) + s) * NHD_ + dd] =
                    (bf16)((acc[mt][nt][reg] + bia) * scale);
            }
        }
    }
}

// ---------------------------------------------------------------------------
// Fused dual-stream MFMA attention with relative-position bias (as R2).
// ---------------------------------------------------------------------------
__global__ __launch_bounds__(256)
void attn_kernel(const bf16* __restrict__ qg, const bf16* __restrict__ kg,
                 const bf16* __restrict__ vg, const bf16* __restrict__ lqg,
                 const bf16* __restrict__ lkg, const bf16* __restrict__ lvg,
                 const float* __restrict__ maskg, const bf16* __restrict__ demb,
                 float* __restrict__ octx, float* __restrict__ olctx)
{
    __shared__ bf16 Qs[64][104];
    __shared__ bf16 Ks[64][104];
    __shared__ bf16 VsT[64][72];
    __shared__ bf16 LVsT[16][72];
    __shared__ bf16 EPs[128 * 72];
    __shared__ bf16 Hs[64][136];
    __shared__ float Ms[64];

    const int t    = threadIdx.x;
    const int w    = t >> 6;
    const int lane = t & 63;
    const int ln   = lane & 15;
    const int quad = lane >> 4;
    const int m0   = w << 4;

    const int bh = blockIdx.y;
    const int b  = bh >> 4;
    const int h  = bh & 15;
    const int l0 = blockIdx.x << 6;

    const bf16* qb  = qg  + (size_t)bh * (S_LEN * HDIM);
    const bf16* kb  = kg  + (size_t)bh * (S_LEN * HDIM);
    const bf16* vb  = vg  + (size_t)bh * (S_LEN * HDIM);
    const bf16* lqb = lqg + (size_t)bh * (S_LEN * LHDIM);
    const bf16* lkb = lkg + (size_t)bh * (S_LEN * LHDIM);
    const bf16* lvb = lvg + (size_t)bh * (S_LEN * LHDIM);

    #pragma unroll
    for (int r = 0; r < 2; r++) {
        int li = r * 256 + t;
        int m = li >> 3, o8 = (li & 7) << 3;
        *(bf16x8*)&Qs[m][o8] = *(const bf16x8*)&qb[(l0 + m) * HDIM + o8];
    }
    if (t < 128) {
        int m = t >> 1, o8 = (t & 1) << 3;
        *(bf16x8*)&Qs[m][64 + o8] = *(const bf16x8*)&lqb[(l0 + m) * LHDIM + o8];
    }
    {
        int m = t >> 2, c0 = 80 + (t & 3) * 6;
        #pragma unroll
        for (int u = 0; u < 6; u++) { Qs[m][c0 + u] = (bf16)0.0f; Ks[m][c0 + u] = (bf16)0.0f; }
    }
    __syncthreads();

    bf16x8 af[3];
    #pragma unroll
    for (int ks = 0; ks < 3; ks++)
        af[ks] = *(const bf16x8*)&Qs[m0 + ln][ks * 32 + quad * 8];

    float mrow[4], lrow[4];
    f32x4 co[4];
    f32x4 cl;
    #pragma unroll
    for (int i = 0; i < 4; i++) { mrow[i] = -1e30f; lrow[i] = 0.0f; co[i] = (f32x4)0.0f; }
    cl = (f32x4)0.0f;

    for (int r0 = 0; r0 < S_LEN; r0 += 64) {
        #pragma unroll
        for (int r = 0; r < 2; r++) {
            int li = r * 256 + t;
            int m = li >> 3, o8 = (li & 7) << 3;
            *(bf16x8*)&Ks[m][o8] = *(const bf16x8*)&kb[(r0 + m) * HDIM + o8];
        }
        if (t < 128) {
            int m = t >> 1, o8 = (t & 1) << 3;
            *(bf16x8*)&Ks[m][64 + o8] = *(const bf16x8*)&lkb[(r0 + m) * LHDIM + o8];
        }
        #pragma unroll
        for (int r = 0; r < 2; r++) {
            int li = r * 256 + t;
            int rr = li >> 3, d8 = (li & 7) << 3;
            bf16x8 x = *(const bf16x8*)&vb[(r0 + rr) * HDIM + d8];
            #pragma unroll
            for (int u = 0; u < 8; u++) VsT[d8 + u][rr] = x[u];
        }
        if (t < 128) {
            int rr = t >> 1, d8 = (t & 1) << 3;
            bf16x8 x = *(const bf16x8*)&lvb[(r0 + rr) * LHDIM + d8];
            #pragma unroll
            for (int u = 0; u < 8; u++) LVsT[d8 + u][rr] = x[u];
        }
        {
            const int jb = l0 - r0 + 1984;
            #pragma unroll
            for (int r = 0; r < 4; r++) {
                int li = r * 256 + t;
                int c = li >> 3, o8 = (li & 7) << 3;
                *(bf16x8*)&EPs[c * 72 + o8] = *(const bf16x8*)&demb[(jb + c) * HDIM + o8];
            }
        }
        if (t < 64) Ms[t] = maskg[b * S_LEN + r0 + t];
        __syncthreads();   // B1

        f32x4 hh[8];
        #pragma unroll
        for (int ct = 0; ct < 8; ct++) {
            hh[ct] = (f32x4)0.0f;
            #pragma unroll
            for (int ks = 0; ks < 2; ks++)
                hh[ct] = MFMA16(af[ks],
                                *(const bf16x8*)&EPs[(ct * 16 + ln) * 72 + ks * 32 + quad * 8],
                                hh[ct]);
        }
        f32x4 sc[4];
        #pragma unroll
        for (int nt = 0; nt < 4; nt++) {
            sc[nt] = (f32x4)0.0f;
            #pragma unroll
            for (int ks = 0; ks < 3; ks++)
                sc[nt] = MFMA16(af[ks],
                                *(const bf16x8*)&Ks[nt * 16 + ln][ks * 32 + quad * 8],
                                sc[nt]);
        }
        #pragma unroll
        for (int ct = 0; ct < 8; ct++)
            #pragma unroll
            for (int reg = 0; reg < 4; reg++)
                Hs[m0 + quad * 4 + reg][ct * 16 + ln] = (bf16)hh[ct][reg];
        __syncthreads();   // B2

        float msv[4];
        #pragma unroll
        for (int nt = 0; nt < 4; nt++) msv[nt] = Ms[nt * 16 + ln];

        float sv[4][4];
        #pragma unroll
        for (int nt = 0; nt < 4; nt++) {
            int n = nt * 16 + ln;
            #pragma unroll
            for (int reg = 0; reg < 4; reg++) {
                int mf = m0 + quad * 4 + reg;
                sv[nt][reg] = sc[nt][reg] + (float)Hs[mf][mf - n + 63] + msv[nt];
            }
        }
        #pragma unroll
        for (int reg = 0; reg < 4; reg++) {
            float rmax = fmaxf(fmaxf(sv[0][reg], sv[1][reg]), fmaxf(sv[2][reg], sv[3][reg]));
            #pragma unroll
            for (int off = 1; off < 16; off <<= 1)
                rmax = fmaxf(rmax, __shfl_xor(rmax, off));
            float mnew  = fmaxf(mrow[reg], rmax);
            float alpha = __expf(mrow[reg] - mnew);
            float rsum = 0.0f;
            #pragma unroll
            for (int nt = 0; nt < 4; nt++) {
                float p = __expf(sv[nt][reg] - mnew);
                sv[nt][reg] = p;
                rsum += p;
            }
            #pragma unroll
            for (int off = 1; off < 16; off <<= 1)
                rsum += __shfl_xor(rsum, off);
            lrow[reg] = lrow[reg] * alpha + rsum;
            mrow[reg] = mnew;
            #pragma unroll
            for (int nt = 0; nt < 4; nt++) co[nt][reg] *= alpha;
            cl[reg] *= alpha;
        }
        #pragma unroll
        for (int nt = 0; nt < 4; nt++)
            #pragma unroll
            for (int reg = 0; reg < 4; reg++)
                EPs[(m0 + quad * 4 + reg) * 72 + nt * 16 + ln] = (bf16)sv[nt][reg];
        __syncthreads();   // B3

        #pragma unroll
        for (int ks = 0; ks < 2; ks++) {
            bf16x8 ap = *(const bf16x8*)&EPs[(m0 + ln) * 72 + ks * 32 + quad * 8];
            cl = MFMA16(ap, *(const bf16x8*)&LVsT[ln][ks * 32 + quad * 8], cl);
            #pragma unroll
            for (int nt = 0; nt < 4; nt++)
                co[nt] = MFMA16(ap,
                                *(const bf16x8*)&VsT[nt * 16 + ln][ks * 32 + quad * 8],
                                co[nt]);
        }
        __syncthreads();   // B4
    }

    #pragma unroll
    for (int reg = 0; reg < 4; reg++) {
        int s = l0 + m0 + quad * 4 + reg;
        float inv = 1.0f / lrow[reg];
        #pragma unroll
        for (int nt = 0; nt < 4; nt++)
            octx[(size_t)(b * S_LEN + s) * 1024 + h * 64 + nt * 16 + ln] = co[nt][reg] * inv;
        olctx[(size_t)(b * S_LEN + s) * 256 + h * 16 + ln] = cl[reg] * inv;
    }
}

// ---------------------------------------------------------------------------
extern "C" void kernel_launch(void* const* d_in, const int* in_sizes, int n_in,
                              void* d_out, int out_size, void* d_ws, size_t ws_size,
                              hipStream_t stream)
{
    (void)in_sizes; (void)n_in; (void)out_size; (void)ws_size;

    const float* hs   = (const float*)d_in[0];
    const float* lin  = (const float*)d_in[1];
    const float* mask = (const float*)d_in[2];
    const float* wq  = (const float*)d_in[3];  const float* bq  = (const float*)d_in[4];
    const float* wk  = (const float*)d_in[5];  const float* bk  = (const float*)d_in[6];
    const float* wv  = (const float*)d_in[7];  const float* bv  = (const float*)d_in[8];
    const float* lwq = (const float*)d_in[9];  const float* lbq = (const float*)d_in[10];
    const float* lwk = (const float*)d_in[11]; const float* lbk = (const float*)d_in[12];
    const float* lwv = (const float*)d_in[13]; const float* lbv = (const float*)d_in[14];
    const float* demb = (const float*)d_in[15];

    bf16* ws = (bf16*)d_ws;
    bf16* q    = ws;                  // 4,194,304
    bf16* k    = ws + 4194304;
    bf16* v    = ws + 8388608;
    bf16* lq   = ws + 12582912;       // 1,048,576
    bf16* lk   = ws + 13631488;
    bf16* lv   = ws + 14680064;
    bf16* de   = ws + 15728640;       // 262,080
    bf16* hsb  = ws + 16000000;       // 4,194,304
    bf16* linb = ws + 20194304;       // 1,048,576
    bf16* wqt  = ws + 21242880;       // 1,048,576
    bf16* wkt  = ws + 22291456;
    bf16* wvt  = ws + 23340032;
    bf16* lwqt = ws + 24388608;       // 65,536
    bf16* lwkt = ws + 24454144;
    bf16* lwvt = ws + 24519680;       // end 24,585,216 el (~49 MB)

    // converts
    cvt4_kernel<<<dim3(4096), 256, 0, stream>>>(hs,  hsb,  1048576);
    cvt4_kernel<<<dim3(1024), 256, 0, stream>>>(lin, linb, 262144);
    cvt4_kernel<<<dim3(256),  256, 0, stream>>>(demb, de,  65520);
    cvtT_kernel<<<dim3(16, 16, 3), 256, 0, stream>>>(wq, wk, wv, wqt, wkt, wvt, 1024, 1024);
    cvtT_kernel<<<dim3(4, 4, 3),   256, 0, stream>>>(lwq, lwk, lwv, lwqt, lwkt, lwvt, 256, 256);

    // MFMA projections
    projm_kernel<1024, 64><<<dim3(8, 32, 3), 256, 0, stream>>>(
        hsb, wqt, bq, wkt, bk, wvt, bv, q, k, v, 0.125f);
    projm_kernel<256, 16><<<dim3(2, 32, 3), 256, 0, stream>>>(
        linb, lwqt, lbq, lwkt, lbk, lwvt, lbv, lq, lk, lv, 0.25f);

    float* octx  = (float*)d_out;
    float* olctx = (float*)d_out + 4194304;
    attn_kernel<<<dim3(16, 64), 256, 0, stream>>>(
        q, k, v, lq, lk, lv, mask, de, octx, olctx);
}